// Round 13
// baseline (179.250 us; speedup 1.0000x reference)
//
#include <hip/hip_runtime.h>

#define N_ 512
#define D_ 128
#define LOG2E 1.44269504088896f

// ws: [0, 8 MB)      xp_t bf16 TRANSPOSED [inst][f=128][s=512]   (8,388,608 B)
//     [8, 10.5 MB)   score_g fp32 [inst][kind:ss/sd][h=8][s=512] (2,097,152 B)
// h staged in d_out; combine mixes in place.

typedef __attribute__((ext_vector_type(8))) short short8;
typedef __attribute__((ext_vector_type(4))) float floatx4;
typedef __attribute__((ext_vector_type(4))) unsigned int uintx4;

#if defined(__has_builtin)
#if __has_builtin(__builtin_amdgcn_exp2f)
#define EXP2F(x) __builtin_amdgcn_exp2f(x)
#else
#define EXP2F(x) exp2f(x)
#endif
#else
#define EXP2F(x) exp2f(x)
#endif

__device__ __forceinline__ unsigned short f2bf(float f) {
    unsigned int u = __float_as_uint(f);
    u += 0x7fffu + ((u >> 16) & 1u);
    return (unsigned short)(u >> 16);
}
__device__ __forceinline__ float bflo(unsigned int u) { return __uint_as_float(u << 16); }
__device__ __forceinline__ float bfhi(unsigned int u) { return __uint_as_float(u & 0xffff0000u); }

// ---------------------------------------------------------------------------
// Kernel 1: proj via MFMA, no LDS/barriers; fused ss AND sd reductions
// (unchanged from R12). 2 blocks per (inst, 64-row ntile).
// ---------------------------------------------------------------------------
__global__ __launch_bounds__(256) void proj_kernel(
    const float* __restrict__ x, const float* __restrict__ W,
    const float* __restrict__ pb, const float* __restrict__ att_src,
    const float* __restrict__ att_dst,
    unsigned short* __restrict__ xpt, float* __restrict__ sg)
{
    const int bid = blockIdx.x;
    const int unit = bid >> 1;      // 0..511
    const int half = bid & 1;
    const int ntile = unit & 7;
    const int inst  = unit >> 3;    // 0..63
    const int j = inst & 1;
    const int bi = inst >> 1;
    const int ij = (bi & 1) * 2 + j;
    const int t = threadIdx.x;
    const int wave = t >> 6, L = t & 63, n = L & 15, q = L >> 4;

    const int n0w = ntile * 64 + wave * 16;
    const float* xrow = x + ((size_t)bi * N_ + n0w + n) * D_ + q * 8;
    short8 Af[4];
#pragma unroll
    for (int kc = 0; kc < 4; ++kc) {
        const float4 a0 = *(const float4*)(xrow + kc * 32);
        const float4 a1 = *(const float4*)(xrow + kc * 32 + 4);
        uintx4 au;
        au.x = f2bf(a0.x) | ((unsigned int)f2bf(a0.y) << 16);
        au.y = f2bf(a0.z) | ((unsigned int)f2bf(a0.w) << 16);
        au.z = f2bf(a1.x) | ((unsigned int)f2bf(a1.y) << 16);
        au.w = f2bf(a1.z) | ((unsigned int)f2bf(a1.w) << 16);
        Af[kc] = __builtin_bit_cast(short8, au);
    }

    const float* wb = W + (size_t)ij * D_ * D_;
#pragma unroll
    for (int ft = 0; ft < 4; ++ft) {
        const int head = half * 4 + ft;
        const int fg = head * 16 + n;
        const float* wrow = wb + (size_t)fg * D_ + q * 8;
        floatx4 C = (floatx4){0.f, 0.f, 0.f, 0.f};
#pragma unroll
        for (int kc = 0; kc < 4; ++kc) {
            const float4 b0 = *(const float4*)(wrow + kc * 32);
            const float4 b1 = *(const float4*)(wrow + kc * 32 + 4);
            uintx4 bu;
            bu.x = f2bf(b0.x) | ((unsigned int)f2bf(b0.y) << 16);
            bu.y = f2bf(b0.z) | ((unsigned int)f2bf(b0.w) << 16);
            bu.z = f2bf(b1.x) | ((unsigned int)f2bf(b1.y) << 16);
            bu.w = f2bf(b1.z) | ((unsigned int)f2bf(b1.w) << 16);
            C = __builtin_amdgcn_mfma_f32_16x16x32_bf16(
                Af[kc], __builtin_bit_cast(short8, bu), C, 0, 0, 0);
        }
        const float pbv = pb[ij * D_ + fg];
        float xp0 = C[0] + pbv, xp1 = C[1] + pbv;
        float xp2 = C[2] + pbv, xp3 = C[3] + pbv;
        uint2 pk;
        pk.x = f2bf(xp0) | ((unsigned int)f2bf(xp1) << 16);
        pk.y = f2bf(xp2) | ((unsigned int)f2bf(xp3) << 16);
        *(uint2*)&xpt[((size_t)inst * D_ + fg) * N_ + n0w + q * 4] = pk;

        const float asv = att_src[ij * D_ + fg];
        const float adv = att_dst[ij * D_ + fg];
        float sa0 = xp0 * asv, sa1 = xp1 * asv, sa2 = xp2 * asv, sa3 = xp3 * asv;
        float sb0 = xp0 * adv, sb1 = xp1 * adv, sb2 = xp2 * adv, sb3 = xp3 * adv;
#pragma unroll
        for (int off = 1; off < 16; off <<= 1) {
            sa0 += __shfl_xor(sa0, off); sa1 += __shfl_xor(sa1, off);
            sa2 += __shfl_xor(sa2, off); sa3 += __shfl_xor(sa3, off);
            sb0 += __shfl_xor(sb0, off); sb1 += __shfl_xor(sb1, off);
            sb2 += __shfl_xor(sb2, off); sb3 += __shfl_xor(sb3, off);
        }
        if (n < 4) {
            const float v = (n == 0) ? sa0 : (n == 1) ? sa1 : (n == 2) ? sa2 : sa3;
            sg[(((size_t)inst * 2 + 0) * 8 + head) * N_ + n0w + q * 4 + n] = v * LOG2E;
        } else if (n >= 8 && n < 12) {
            const int r = n - 8;
            const float v = (r == 0) ? sb0 : (r == 1) ? sb1 : (r == 2) ? sb2 : sb3;
            sg[(((size_t)inst * 2 + 1) * 8 + head) * N_ + n0w + q * 4 + r] = v * LOG2E;
        }
    }
}

// ---------------------------------------------------------------------------
// Kernel 2: attention via MFMA. 2048 blocks: hhalf = bid&1, tile = (bid>>1)
// &31, bi = bid>>6. 4 waves; wave owns ONE head (h = hhalf*4 + wave), both
// convs fused in one barrier-free K-loop. LDS 20.25 KB -> ~7 blocks/CU
// (~28 waves/CU, was 16). Z via second MFMA against all-ones B. v_perm pack
// truncates w to bf16 so Z and numerator match. Masked: w = exp(0) = 1.
// Exactly ONE __syncthreads per block. Consecutive bids share (bi,tile) so
// the duplicated A read hits L2/L3.
// ---------------------------------------------------------------------------
__global__ __launch_bounds__(256) void attn_kernel(
    const unsigned short* __restrict__ xpt,
    const float* __restrict__ sg,
    const int* __restrict__ A,
    const float* __restrict__ bias,
    float* __restrict__ hout)
{
    __shared__ float ss_t[2][4][N_];         // 16 KB [conv][hh][s], log2-domain
    __shared__ unsigned int mask_l[2][N_];   // 4 KB

    const int bid = blockIdx.x;
    const int hhalf = bid & 1;
    const int tile = (bid >> 1) & 31;
    const int bi   = bid >> 6;
    const int i_ = bi & 1;
    const int d0 = tile * 16;
    const int t = threadIdx.x;
    const int wave = t >> 6, L = t & 63, n = L & 15, q = L >> 4;
    const int h = hhalf * 4 + wave;      // this wave's head

    // edge bitmasks for both convs (bit k = dst d0+k)
#pragma unroll
    for (int rep = 0; rep < 2; ++rep) {
        const int s = t + rep * 256;
        const int* Ar = A + ((size_t)bi * N_ + s) * N_ + d0;
        unsigned int m0 = 0, m1 = 0;
#pragma unroll
        for (int g = 0; g < 4; ++g) {
            const int4 v = *(const int4*)(Ar + g * 4);
            const int k = g * 4;
            if (v.x == 2 || v.x == 4) m0 |= 1u << (k + 0);
            if (v.x == 3 || v.x == 4) m1 |= 1u << (k + 0);
            if (v.y == 2 || v.y == 4) m0 |= 1u << (k + 1);
            if (v.y == 3 || v.y == 4) m1 |= 1u << (k + 1);
            if (v.z == 2 || v.z == 4) m0 |= 1u << (k + 2);
            if (v.z == 3 || v.z == 4) m1 |= 1u << (k + 2);
            if (v.w == 2 || v.w == 4) m0 |= 1u << (k + 3);
            if (v.w == 3 || v.w == 4) m1 |= 1u << (k + 3);
        }
        mask_l[0][s] = m0;
        mask_l[1][s] = m1;
    }

    // stage ss for this block's 4 heads x 2 convs: 512 float4 per conv
#pragma unroll
    for (int j = 0; j < 2; ++j) {
        const float4* src = (const float4*)(sg
            + ((size_t)(bi * 2 + j) * 2 * 8 + hhalf * 4) * N_);
        float4* dst = (float4*)&ss_t[j][0][0];
#pragma unroll
        for (int r = 0; r < 2; ++r) dst[r * 256 + t] = src[r * 256 + t];
    }

    // sd for this wave's head (broadcast within quad rows)
    float sdv[2];
#pragma unroll
    for (int j = 0; j < 2; ++j)
        sdv[j] = sg[(((size_t)(bi * 2 + j) * 2 + 1) * 8 + h) * N_ + d0 + n];

    __syncthreads();   // masks + ss_t ready (the ONLY barrier)

    const unsigned short* xpi[2] = { xpt + (size_t)(bi * 2) * D_ * N_,
                                     xpt + (size_t)(bi * 2 + 1) * D_ * N_ };

    const uintx4 ou = { 0x3F803F80u, 0x3F803F80u, 0x3F803F80u, 0x3F803F80u };
    const short8 onesB = __builtin_bit_cast(short8, ou);

    floatx4 Cacc[2], Cz[2];
#pragma unroll
    for (int j = 0; j < 2; ++j) {
        Cacc[j] = (floatx4){0.f, 0.f, 0.f, 0.f};
        Cz[j]   = (floatx4){0.f, 0.f, 0.f, 0.f};
    }

    for (int c = 0; c < 16; ++c) {
        const int sq = c * 32 + q * 8;
        short8 Bf[2];
        Bf[0] = *(const short8*)(xpi[0] + (size_t)(h * 16 + n) * N_ + sq);
        Bf[1] = *(const short8*)(xpi[1] + (size_t)(h * 16 + n) * N_ + sq);
        const uint4 ma0 = *(const uint4*)&mask_l[0][sq];
        const uint4 ma1 = *(const uint4*)&mask_l[0][sq + 4];
        const uint4 mb0 = *(const uint4*)&mask_l[1][sq];
        const uint4 mb1 = *(const uint4*)&mask_l[1][sq + 4];
        const unsigned int mw[2][8] = {
            { ma0.x, ma0.y, ma0.z, ma0.w, ma1.x, ma1.y, ma1.z, ma1.w },
            { mb0.x, mb0.y, mb0.z, mb0.w, mb1.x, mb1.y, mb1.z, mb1.w } };
#pragma unroll
        for (int j = 0; j < 2; ++j) {
            const float4 s0v = *(const float4*)&ss_t[j][wave][sq];
            const float4 s1v = *(const float4*)&ss_t[j][wave][sq + 4];
            const float ssv[8] = { s0v.x, s0v.y, s0v.z, s0v.w,
                                   s1v.x, s1v.y, s1v.z, s1v.w };
            unsigned int wt[8];
#pragma unroll
            for (int idx = 0; idx < 8; ++idx) {
                const float z0 = ssv[idx] + sdv[j];
                const float zr = fmaxf(z0, 0.2f * z0);
                const float e = EXP2F(zr);
                wt[idx] = __float_as_uint(((mw[j][idx] >> n) & 1u) ? e : 1.0f);
            }
            uintx4 au;   // v_perm keeps bytes 3:2 of each src = bf16 trunc
            au.x = __builtin_amdgcn_perm(wt[1], wt[0], 0x07060302);
            au.y = __builtin_amdgcn_perm(wt[3], wt[2], 0x07060302);
            au.z = __builtin_amdgcn_perm(wt[5], wt[4], 0x07060302);
            au.w = __builtin_amdgcn_perm(wt[7], wt[6], 0x07060302);
            const short8 As = __builtin_bit_cast(short8, au);
            Cacc[j] = __builtin_amdgcn_mfma_f32_16x16x32_bf16(
                As, Bf[j], Cacc[j], 0, 0, 0);
            Cz[j] = __builtin_amdgcn_mfma_f32_16x16x32_bf16(
                As, onesB, Cz[j], 0, 0, 0);
        }
    }

    // epilogue: hacc = sum_j [ C/Z + xp_self + bias ]
    float hacc[4] = { 0.f, 0.f, 0.f, 0.f };
#pragma unroll
    for (int j = 0; j < 2; ++j) {
        const int ij = i_ * 2 + j;
        const float bv = bias[ij * D_ + h * 16 + n];
        const uint2 sv = *(const uint2*)(xpi[j] + (size_t)(h * 16 + n) * N_ + d0 + q * 4);
        const float selfv[4] = { bflo(sv.x), bfhi(sv.x), bflo(sv.y), bfhi(sv.y) };
#pragma unroll
        for (int reg = 0; reg < 4; ++reg) {
            const float Zi = 1.0f / Cz[j][reg];
            hacc[reg] += Cacc[j][reg] * Zi + selfv[reg] + bv;
        }
    }

#pragma unroll
    for (int reg = 0; reg < 4; ++reg)
        hout[((size_t)bi * N_ + d0 + q * 4 + reg) * D_ + h * 16 + n] = hacc[reg];
}

// ---------------------------------------------------------------------------
// Kernel 3: in-place mix on d_out (thread owns both i slices of one b).
// ---------------------------------------------------------------------------
__global__ __launch_bounds__(256) void combine_kernel(float* __restrict__ h)
{
    const int idx = blockIdx.x * 256 + threadIdx.x;
    const int b = idx >> 14;
    const int r = idx & 16383;
    float4* p0 = (float4*)h + (size_t)b * 32768 + r;
    float4* p1 = p0 + 16384;
    const float4 a = *p0;
    const float4 o = *p1;
    float4 r0, r1;
    r0.x = 1.5f * a.x + 0.5f * o.x;  r1.x = 1.5f * o.x + 0.5f * a.x;
    r0.y = 1.5f * a.y + 0.5f * o.y;  r1.y = 1.5f * o.y + 0.5f * a.y;
    r0.z = 1.5f * a.z + 0.5f * o.z;  r1.z = 1.5f * o.z + 0.5f * a.z;
    r0.w = 1.5f * a.w + 0.5f * o.w;  r1.w = 1.5f * o.w + 0.5f * a.w;
    *p0 = r0;
    *p1 = r1;
}

extern "C" void kernel_launch(void* const* d_in, const int* in_sizes, int n_in,
                              void* d_out, int out_size, void* d_ws, size_t ws_size,
                              hipStream_t stream)
{
    const float* x   = (const float*)d_in[0];
    const int*   A   = (const int*)d_in[1];
    const float* W   = (const float*)d_in[2];
    const float* pb  = (const float*)d_in[3];
    const float* as_ = (const float*)d_in[4];
    const float* ad_ = (const float*)d_in[5];
    const float* bs  = (const float*)d_in[6];

    unsigned short* xpt = (unsigned short*)d_ws;          // 8,388,608 B
    float* sg = (float*)(xpt + (size_t)64 * D_ * N_);     // +2,097,152 B
    float* h = (float*)d_out;

    proj_kernel<<<1024, 256, 0, stream>>>(x, W, pb, as_, ad_, xpt, sg);
    attn_kernel<<<2048, 256, 0, stream>>>(xpt, sg, A, bs, h);
    combine_kernel<<<1024, 256, 0, stream>>>(h);
}

// Round 14
// 164.929 us; speedup vs baseline: 1.0868x; 1.0868x over previous
//
#include <hip/hip_runtime.h>

#define N_ 512
#define D_ 128
#define LOG2E 1.44269504088896f

// ws: [0, 8 MB)        xp_t bf16 TRANSPOSED [inst][f=128][s=512]   (8,388,608 B)
//     [8, 10 MB)       score_g fp32 [inst][kind:ss/sd][h=8][s=512] (2,097,152 B)
//     [10, 12 MB)      mask_g u16 [inst][tile=32][s=512]           (2,097,152 B)
// d_out zeroed (hipMemsetAsync), conv contributions atomically added,
// combine mixes in place. Exactly 2 adders/address -> deterministic.

typedef __attribute__((ext_vector_type(8))) short short8;
typedef __attribute__((ext_vector_type(4))) float floatx4;
typedef __attribute__((ext_vector_type(4))) unsigned int uintx4;

#if defined(__has_builtin)
#if __has_builtin(__builtin_amdgcn_exp2f)
#define EXP2F(x) __builtin_amdgcn_exp2f(x)
#else
#define EXP2F(x) exp2f(x)
#endif
#else
#define EXP2F(x) exp2f(x)
#endif

__device__ __forceinline__ unsigned short f2bf(float f) {
    unsigned int u = __float_as_uint(f);
    u += 0x7fffu + ((u >> 16) & 1u);
    return (unsigned short)(u >> 16);
}
__device__ __forceinline__ float bflo(unsigned int u) { return __uint_as_float(u << 16); }
__device__ __forceinline__ float bfhi(unsigned int u) { return __uint_as_float(u & 0xffff0000u); }

// ---------------------------------------------------------------------------
// Kernel 0: A (int32, 32 MB) -> edge bitmasks mg[inst][tile][s] u16 (2 MB).
// Block = (bi, 16-s tile); thread = (sl = t>>4, lane = t&15 covering 32 dst).
// ---------------------------------------------------------------------------
__global__ __launch_bounds__(256) void maskprep_kernel(
    const int* __restrict__ A, unsigned short* __restrict__ mg)
{
    const int bid = blockIdx.x;       // 32 bi x 32 stile
    const int stile = bid & 31;
    const int bi = bid >> 5;
    const int t = threadIdx.x;
    const int sl = t >> 4, lane = t & 15;
    const int s = stile * 16 + sl;
    const int* Ar = A + ((size_t)bi * N_ + s) * N_ + lane * 32;
    unsigned int m0 = 0, m1 = 0;
#pragma unroll
    for (int g = 0; g < 8; ++g) {
        const int4 v = *(const int4*)(Ar + g * 4);
        const int k = g * 4;
        if (v.x == 2 || v.x == 4) m0 |= 1u << (k + 0);
        if (v.x == 3 || v.x == 4) m1 |= 1u << (k + 0);
        if (v.y == 2 || v.y == 4) m0 |= 1u << (k + 1);
        if (v.y == 3 || v.y == 4) m1 |= 1u << (k + 1);
        if (v.z == 2 || v.z == 4) m0 |= 1u << (k + 2);
        if (v.z == 3 || v.z == 4) m1 |= 1u << (k + 2);
        if (v.w == 2 || v.w == 4) m0 |= 1u << (k + 3);
        if (v.w == 3 || v.w == 4) m1 |= 1u << (k + 3);
    }
    const size_t b0 = ((size_t)bi * 2 + 0) * 32 * N_;   // inst = bi*2 + conv
    const size_t b1 = ((size_t)bi * 2 + 1) * 32 * N_;
    const int T0 = lane * 2, T1 = lane * 2 + 1;
    mg[b0 + (size_t)T0 * N_ + s] = (unsigned short)(m0 & 0xFFFFu);
    mg[b0 + (size_t)T1 * N_ + s] = (unsigned short)(m0 >> 16);
    mg[b1 + (size_t)T0 * N_ + s] = (unsigned short)(m1 & 0xFFFFu);
    mg[b1 + (size_t)T1 * N_ + s] = (unsigned short)(m1 >> 16);
}

// ---------------------------------------------------------------------------
// Kernel 1: proj via MFMA, no LDS/barriers; fused ss AND sd reductions
// (unchanged from R12). 2 blocks per (inst, 64-row ntile).
// ---------------------------------------------------------------------------
__global__ __launch_bounds__(256) void proj_kernel(
    const float* __restrict__ x, const float* __restrict__ W,
    const float* __restrict__ pb, const float* __restrict__ att_src,
    const float* __restrict__ att_dst,
    unsigned short* __restrict__ xpt, float* __restrict__ sg)
{
    const int bid = blockIdx.x;
    const int unit = bid >> 1;      // 0..511
    const int half = bid & 1;
    const int ntile = unit & 7;
    const int inst  = unit >> 3;    // 0..63
    const int j = inst & 1;
    const int bi = inst >> 1;
    const int ij = (bi & 1) * 2 + j;
    const int t = threadIdx.x;
    const int wave = t >> 6, L = t & 63, n = L & 15, q = L >> 4;

    const int n0w = ntile * 64 + wave * 16;
    const float* xrow = x + ((size_t)bi * N_ + n0w + n) * D_ + q * 8;
    short8 Af[4];
#pragma unroll
    for (int kc = 0; kc < 4; ++kc) {
        const float4 a0 = *(const float4*)(xrow + kc * 32);
        const float4 a1 = *(const float4*)(xrow + kc * 32 + 4);
        uintx4 au;
        au.x = f2bf(a0.x) | ((unsigned int)f2bf(a0.y) << 16);
        au.y = f2bf(a0.z) | ((unsigned int)f2bf(a0.w) << 16);
        au.z = f2bf(a1.x) | ((unsigned int)f2bf(a1.y) << 16);
        au.w = f2bf(a1.z) | ((unsigned int)f2bf(a1.w) << 16);
        Af[kc] = __builtin_bit_cast(short8, au);
    }

    const float* wb = W + (size_t)ij * D_ * D_;
#pragma unroll
    for (int ft = 0; ft < 4; ++ft) {
        const int head = half * 4 + ft;
        const int fg = head * 16 + n;
        const float* wrow = wb + (size_t)fg * D_ + q * 8;
        floatx4 C = (floatx4){0.f, 0.f, 0.f, 0.f};
#pragma unroll
        for (int kc = 0; kc < 4; ++kc) {
            const float4 b0 = *(const float4*)(wrow + kc * 32);
            const float4 b1 = *(const float4*)(wrow + kc * 32 + 4);
            uintx4 bu;
            bu.x = f2bf(b0.x) | ((unsigned int)f2bf(b0.y) << 16);
            bu.y = f2bf(b0.z) | ((unsigned int)f2bf(b0.w) << 16);
            bu.z = f2bf(b1.x) | ((unsigned int)f2bf(b1.y) << 16);
            bu.w = f2bf(b1.z) | ((unsigned int)f2bf(b1.w) << 16);
            C = __builtin_amdgcn_mfma_f32_16x16x32_bf16(
                Af[kc], __builtin_bit_cast(short8, bu), C, 0, 0, 0);
        }
        const float pbv = pb[ij * D_ + fg];
        float xp0 = C[0] + pbv, xp1 = C[1] + pbv;
        float xp2 = C[2] + pbv, xp3 = C[3] + pbv;
        uint2 pk;
        pk.x = f2bf(xp0) | ((unsigned int)f2bf(xp1) << 16);
        pk.y = f2bf(xp2) | ((unsigned int)f2bf(xp3) << 16);
        *(uint2*)&xpt[((size_t)inst * D_ + fg) * N_ + n0w + q * 4] = pk;

        const float asv = att_src[ij * D_ + fg];
        const float adv = att_dst[ij * D_ + fg];
        float sa0 = xp0 * asv, sa1 = xp1 * asv, sa2 = xp2 * asv, sa3 = xp3 * asv;
        float sb0 = xp0 * adv, sb1 = xp1 * adv, sb2 = xp2 * adv, sb3 = xp3 * adv;
#pragma unroll
        for (int off = 1; off < 16; off <<= 1) {
            sa0 += __shfl_xor(sa0, off); sa1 += __shfl_xor(sa1, off);
            sa2 += __shfl_xor(sa2, off); sa3 += __shfl_xor(sa3, off);
            sb0 += __shfl_xor(sb0, off); sb1 += __shfl_xor(sb1, off);
            sb2 += __shfl_xor(sb2, off); sb3 += __shfl_xor(sb3, off);
        }
        if (n < 4) {
            const float v = (n == 0) ? sa0 : (n == 1) ? sa1 : (n == 2) ? sa2 : sa3;
            sg[(((size_t)inst * 2 + 0) * 8 + head) * N_ + n0w + q * 4 + n] = v * LOG2E;
        } else if (n >= 8 && n < 12) {
            const int r = n - 8;
            const float v = (r == 0) ? sb0 : (r == 1) ? sb1 : (r == 2) ? sb2 : sb3;
            sg[(((size_t)inst * 2 + 1) * 8 + head) * N_ + n0w + q * 4 + r] = v * LOG2E;
        }
    }
}

// ---------------------------------------------------------------------------
// Kernel 2: attention via MFMA, split by conv. 2048 blocks: tile = bid&31,
// conv = (bid>>5)&1, bi = bid>>6 (consecutive bids share the xpt/sg slab for
// L2). 4 waves, wave owns 2 heads of one conv. LDS 17.25 KB -> 8 blocks/CU
// (32 waves/CU). Masks precomputed (1 KB LDS); ss/sd precomputed by proj.
// Z via second MFMA vs all-ones B; v_perm pack truncates w to bf16 so Z and
// numerator match. Masked: w = exp(0) = 1. Per-conv term C/Z + xp_self +
// bias is self-contained -> unsafeAtomicAdd into zeroed d_out (2 adders per
// address, exact & order-independent). ONE __syncthreads per block.
// ---------------------------------------------------------------------------
__global__ __launch_bounds__(256) void attn_kernel(
    const unsigned short* __restrict__ xpt,
    const float* __restrict__ sg,
    const unsigned short* __restrict__ mg,
    const float* __restrict__ bias,
    float* __restrict__ hout)
{
    __shared__ float ss_l[8 * N_];          // 16 KB [h][s], log2-domain
    __shared__ unsigned short mask_l[N_];   // 1 KB

    const int bid = blockIdx.x;
    const int tile = bid & 31;
    const int cj   = (bid >> 5) & 1;
    const int bi   = bid >> 6;
    const int inst = bi * 2 + cj;
    const int ij = (bi & 1) * 2 + cj;
    const int d0 = tile * 16;
    const int t = threadIdx.x;
    const int wave = t >> 6, L = t & 63, n = L & 15, q = L >> 4;
    const int h0 = wave * 2;
    const int n16 = n + 16;

    // stage ss (4096 floats) + masks (512 u16)
    {
        const float4* src = (const float4*)(sg + (size_t)inst * 2 * 8 * N_);
        float4* dst = (float4*)ss_l;
#pragma unroll
        for (int r = 0; r < 4; ++r) dst[r * 256 + t] = src[r * 256 + t];
    }
    if (t < 64)
        ((uint4*)mask_l)[t] =
            ((const uint4*)(mg + ((size_t)inst * 32 + tile) * N_))[t];

    float sdv[2];
#pragma unroll
    for (int hh = 0; hh < 2; ++hh)
        sdv[hh] = sg[(((size_t)inst * 2 + 1) * 8 + h0 + hh) * N_ + d0 + n];

    __syncthreads();   // the ONLY barrier

    const unsigned short* xpi = xpt + (size_t)inst * D_ * N_;

    const uintx4 ou = { 0x3F803F80u, 0x3F803F80u, 0x3F803F80u, 0x3F803F80u };
    const short8 onesB = __builtin_bit_cast(short8, ou);

    floatx4 Cacc[2] = { (floatx4){0.f,0.f,0.f,0.f}, (floatx4){0.f,0.f,0.f,0.f} };
    floatx4 Cz[2]   = { (floatx4){0.f,0.f,0.f,0.f}, (floatx4){0.f,0.f,0.f,0.f} };

    // software-prefetched, barrier-free K loop: 16 chunks of 32 s
    short8 Bf0 = *(const short8*)(xpi + (size_t)(h0 * 16 + n) * N_ + q * 8);
    short8 Bf1 = *(const short8*)(xpi + (size_t)((h0 + 1) * 16 + n) * N_ + q * 8);
    for (int c = 0; c < 16; ++c) {
        const int sq = c * 32 + q * 8;
        short8 nB0, nB1;
        if (c < 15) {
            nB0 = *(const short8*)(xpi + (size_t)(h0 * 16 + n) * N_ + sq + 32);
            nB1 = *(const short8*)(xpi + (size_t)((h0 + 1) * 16 + n) * N_ + sq + 32);
        }
        const uint4 mv = *(const uint4*)&mask_l[sq];   // 8 u16 masks
        const unsigned int mw[4] = { mv.x, mv.y, mv.z, mv.w };
#pragma unroll
        for (int hh = 0; hh < 2; ++hh) {
            const float4 s0v = *(const float4*)&ss_l[(h0 + hh) * N_ + sq];
            const float4 s1v = *(const float4*)&ss_l[(h0 + hh) * N_ + sq + 4];
            const float ssv[8] = { s0v.x, s0v.y, s0v.z, s0v.w,
                                   s1v.x, s1v.y, s1v.z, s1v.w };
            unsigned int wt[8];
#pragma unroll
            for (int idx = 0; idx < 8; ++idx) {
                const float z0 = ssv[idx] + sdv[hh];
                const float zr = fmaxf(z0, 0.2f * z0);
                const float e = EXP2F(zr);
                const unsigned int bit =
                    (mw[idx >> 1] >> ((idx & 1) ? n16 : n)) & 1u;
                wt[idx] = __float_as_uint(bit ? e : 1.0f);
            }
            uintx4 au;   // v_perm keeps bytes 3:2 of each src = bf16 trunc
            au.x = __builtin_amdgcn_perm(wt[1], wt[0], 0x07060302);
            au.y = __builtin_amdgcn_perm(wt[3], wt[2], 0x07060302);
            au.z = __builtin_amdgcn_perm(wt[5], wt[4], 0x07060302);
            au.w = __builtin_amdgcn_perm(wt[7], wt[6], 0x07060302);
            const short8 As = __builtin_bit_cast(short8, au);
            Cacc[hh] = __builtin_amdgcn_mfma_f32_16x16x32_bf16(
                As, hh ? Bf1 : Bf0, Cacc[hh], 0, 0, 0);
            Cz[hh] = __builtin_amdgcn_mfma_f32_16x16x32_bf16(
                As, onesB, Cz[hh], 0, 0, 0);
        }
        Bf0 = nB0;
        Bf1 = nB1;
    }

    // epilogue: atomically add this conv's full term
#pragma unroll
    for (int hh = 0; hh < 2; ++hh) {
        const int h = h0 + hh;
        const float bv = bias[ij * D_ + h * 16 + n];
        const uint2 sv = *(const uint2*)(xpi + (size_t)(h * 16 + n) * N_ + d0 + q * 4);
        const float selfv[4] = { bflo(sv.x), bfhi(sv.x), bflo(sv.y), bfhi(sv.y) };
#pragma unroll
        for (int reg = 0; reg < 4; ++reg) {
            const float Zi = 1.0f / Cz[hh][reg];
            const float val = Cacc[hh][reg] * Zi + selfv[reg] + bv;
            unsafeAtomicAdd(
                &hout[((size_t)bi * N_ + d0 + q * 4 + reg) * D_ + h * 16 + n], val);
        }
    }
}

// ---------------------------------------------------------------------------
// Kernel 3: in-place mix on d_out (thread owns both i slices of one b).
// ---------------------------------------------------------------------------
__global__ __launch_bounds__(256) void combine_kernel(float* __restrict__ h)
{
    const int idx = blockIdx.x * 256 + threadIdx.x;
    const int b = idx >> 14;
    const int r = idx & 16383;
    float4* p0 = (float4*)h + (size_t)b * 32768 + r;
    float4* p1 = p0 + 16384;
    const float4 a = *p0;
    const float4 o = *p1;
    float4 r0, r1;
    r0.x = 1.5f * a.x + 0.5f * o.x;  r1.x = 1.5f * o.x + 0.5f * a.x;
    r0.y = 1.5f * a.y + 0.5f * o.y;  r1.y = 1.5f * o.y + 0.5f * a.y;
    r0.z = 1.5f * a.z + 0.5f * o.z;  r1.z = 1.5f * o.z + 0.5f * a.z;
    r0.w = 1.5f * a.w + 0.5f * o.w;  r1.w = 1.5f * o.w + 0.5f * a.w;
    *p0 = r0;
    *p1 = r1;
}

extern "C" void kernel_launch(void* const* d_in, const int* in_sizes, int n_in,
                              void* d_out, int out_size, void* d_ws, size_t ws_size,
                              hipStream_t stream)
{
    const float* x   = (const float*)d_in[0];
    const int*   A   = (const int*)d_in[1];
    const float* W   = (const float*)d_in[2];
    const float* pb  = (const float*)d_in[3];
    const float* as_ = (const float*)d_in[4];
    const float* ad_ = (const float*)d_in[5];
    const float* bs  = (const float*)d_in[6];

    unsigned short* xpt = (unsigned short*)d_ws;          // 8,388,608 B
    float* sg = (float*)(xpt + (size_t)64 * D_ * N_);     // +2,097,152 B
    unsigned short* mg = (unsigned short*)(sg + (size_t)64 * 2 * 8 * N_); // +2 MB
    float* h = (float*)d_out;

    hipMemsetAsync(d_out, 0, (size_t)out_size * sizeof(float), stream);
    maskprep_kernel<<<1024, 256, 0, stream>>>(A, mg);
    proj_kernel<<<1024, 256, 0, stream>>>(x, W, pb, as_, ad_, xpt, sg);
    attn_kernel<<<2048, 256, 0, stream>>>(xpt, sg, mg, bs, h);
    combine_kernel<<<1024, 256, 0, stream>>>(h);
}

// Round 15
// 159.478 us; speedup vs baseline: 1.1240x; 1.0342x over previous
//
#include <hip/hip_runtime.h>

#define N_ 512
#define D_ 128
#define LOG2E 1.44269504088896f

// ws: [0, 8 MB)    xp_t bf16 TRANSPOSED [inst][f=128][s=512]       (8,388,608 B)
//     [8, 9 MB)    sgE u32 [inst][h=8][s=512]  (Es|Fs packed bf16) (1,048,576 B)
//     [9, 11 MB)   sgD float2 [inst][h=8][s=512] (Ed, Fd fp32)     (2,097,152 B)
//     [11, 13 MB)  mask_g u16 [inst][tile=32][s=512]               (2,097,152 B)
// Factorized softmax: w = exp(leaky(ss+sd)) = max(Es*Ed, Fs*Fd); per-dst
// scale Ed cancels in Cacc/Cz, so the K-loop uses w' = max(Es, Fs*rd),
// masked w' = 1/Ed — NO transcendentals in the hot loop.
// d_out zeroed, conv contributions atomically added (2 adders/address,
// deterministic), combine mixes in place.

typedef __attribute__((ext_vector_type(8))) short short8;
typedef __attribute__((ext_vector_type(4))) float floatx4;
typedef __attribute__((ext_vector_type(4))) unsigned int uintx4;

#if defined(__has_builtin)
#if __has_builtin(__builtin_amdgcn_exp2f)
#define EXP2F(x) __builtin_amdgcn_exp2f(x)
#else
#define EXP2F(x) exp2f(x)
#endif
#else
#define EXP2F(x) exp2f(x)
#endif

__device__ __forceinline__ unsigned short f2bf(float f) {
    unsigned int u = __float_as_uint(f);
    u += 0x7fffu + ((u >> 16) & 1u);
    return (unsigned short)(u >> 16);
}
__device__ __forceinline__ float bflo(unsigned int u) { return __uint_as_float(u << 16); }
__device__ __forceinline__ float bfhi(unsigned int u) { return __uint_as_float(u & 0xffff0000u); }

// ---------------------------------------------------------------------------
// Kernel 1 (fused prep): blocks 0..1023 = proj (MFMA, no LDS/barriers, fused
// score reductions -> Es/Fs packed bf16 + Ed/Fd fp32); blocks 1024..2047 =
// maskprep (A -> per-tile u16 edge bitmasks). Independent work, one dispatch.
// ---------------------------------------------------------------------------
__global__ __launch_bounds__(256) void prep_kernel(
    const float* __restrict__ x, const float* __restrict__ W,
    const float* __restrict__ pb, const float* __restrict__ att_src,
    const float* __restrict__ att_dst, const int* __restrict__ A,
    unsigned short* __restrict__ xpt, unsigned int* __restrict__ sgE,
    float2* __restrict__ sgD, unsigned short* __restrict__ mg)
{
    const int bid0 = blockIdx.x;
    const int t = threadIdx.x;

    if (bid0 >= 1024) {
        // ------------- maskprep: block = (bi, 16-s tile) -------------
        const int bid = bid0 - 1024;
        const int stile = bid & 31;
        const int bi = bid >> 5;
        const int sl = t >> 4, lane = t & 15;
        const int s = stile * 16 + sl;
        const int* Ar = A + ((size_t)bi * N_ + s) * N_ + lane * 32;
        unsigned int m0 = 0, m1 = 0;
#pragma unroll
        for (int g = 0; g < 8; ++g) {
            const int4 v = *(const int4*)(Ar + g * 4);
            const int k = g * 4;
            if (v.x == 2 || v.x == 4) m0 |= 1u << (k + 0);
            if (v.x == 3 || v.x == 4) m1 |= 1u << (k + 0);
            if (v.y == 2 || v.y == 4) m0 |= 1u << (k + 1);
            if (v.y == 3 || v.y == 4) m1 |= 1u << (k + 1);
            if (v.z == 2 || v.z == 4) m0 |= 1u << (k + 2);
            if (v.z == 3 || v.z == 4) m1 |= 1u << (k + 2);
            if (v.w == 2 || v.w == 4) m0 |= 1u << (k + 3);
            if (v.w == 3 || v.w == 4) m1 |= 1u << (k + 3);
        }
        const size_t b0 = ((size_t)bi * 2 + 0) * 32 * N_;
        const size_t b1 = ((size_t)bi * 2 + 1) * 32 * N_;
        const int T0 = lane * 2, T1 = lane * 2 + 1;
        mg[b0 + (size_t)T0 * N_ + s] = (unsigned short)(m0 & 0xFFFFu);
        mg[b0 + (size_t)T1 * N_ + s] = (unsigned short)(m0 >> 16);
        mg[b1 + (size_t)T0 * N_ + s] = (unsigned short)(m1 & 0xFFFFu);
        mg[b1 + (size_t)T1 * N_ + s] = (unsigned short)(m1 >> 16);
        return;
    }

    // ------------- proj: 2 blocks per (inst, 64-row ntile) -------------
    const int unit = bid0 >> 1;
    const int half = bid0 & 1;
    const int ntile = unit & 7;
    const int inst  = unit >> 3;
    const int j = inst & 1;
    const int bi = inst >> 1;
    const int ij = (bi & 1) * 2 + j;
    const int wave = t >> 6, L = t & 63, n = L & 15, q = L >> 4;

    const int n0w = ntile * 64 + wave * 16;
    const float* xrow = x + ((size_t)bi * N_ + n0w + n) * D_ + q * 8;
    short8 Af[4];
#pragma unroll
    for (int kc = 0; kc < 4; ++kc) {
        const float4 a0 = *(const float4*)(xrow + kc * 32);
        const float4 a1 = *(const float4*)(xrow + kc * 32 + 4);
        uintx4 au;
        au.x = f2bf(a0.x) | ((unsigned int)f2bf(a0.y) << 16);
        au.y = f2bf(a0.z) | ((unsigned int)f2bf(a0.w) << 16);
        au.z = f2bf(a1.x) | ((unsigned int)f2bf(a1.y) << 16);
        au.w = f2bf(a1.z) | ((unsigned int)f2bf(a1.w) << 16);
        Af[kc] = __builtin_bit_cast(short8, au);
    }

    const float* wb = W + (size_t)ij * D_ * D_;
#pragma unroll
    for (int ft = 0; ft < 4; ++ft) {
        const int head = half * 4 + ft;
        const int fg = head * 16 + n;
        const float* wrow = wb + (size_t)fg * D_ + q * 8;
        floatx4 C = (floatx4){0.f, 0.f, 0.f, 0.f};
#pragma unroll
        for (int kc = 0; kc < 4; ++kc) {
            const float4 b0 = *(const float4*)(wrow + kc * 32);
            const float4 b1 = *(const float4*)(wrow + kc * 32 + 4);
            uintx4 bu;
            bu.x = f2bf(b0.x) | ((unsigned int)f2bf(b0.y) << 16);
            bu.y = f2bf(b0.z) | ((unsigned int)f2bf(b0.w) << 16);
            bu.z = f2bf(b1.x) | ((unsigned int)f2bf(b1.y) << 16);
            bu.w = f2bf(b1.z) | ((unsigned int)f2bf(b1.w) << 16);
            C = __builtin_amdgcn_mfma_f32_16x16x32_bf16(
                Af[kc], __builtin_bit_cast(short8, bu), C, 0, 0, 0);
        }
        const float pbv = pb[ij * D_ + fg];
        float xp0 = C[0] + pbv, xp1 = C[1] + pbv;
        float xp2 = C[2] + pbv, xp3 = C[3] + pbv;
        uint2 pk;
        pk.x = f2bf(xp0) | ((unsigned int)f2bf(xp1) << 16);
        pk.y = f2bf(xp2) | ((unsigned int)f2bf(xp3) << 16);
        *(uint2*)&xpt[((size_t)inst * D_ + fg) * N_ + n0w + q * 4] = pk;

        const float asv = att_src[ij * D_ + fg];
        const float adv = att_dst[ij * D_ + fg];
        float sa0 = xp0 * asv, sa1 = xp1 * asv, sa2 = xp2 * asv, sa3 = xp3 * asv;
        float sb0 = xp0 * adv, sb1 = xp1 * adv, sb2 = xp2 * adv, sb3 = xp3 * adv;
#pragma unroll
        for (int off = 1; off < 16; off <<= 1) {
            sa0 += __shfl_xor(sa0, off); sa1 += __shfl_xor(sa1, off);
            sa2 += __shfl_xor(sa2, off); sa3 += __shfl_xor(sa3, off);
            sb0 += __shfl_xor(sb0, off); sb1 += __shfl_xor(sb1, off);
            sb2 += __shfl_xor(sb2, off); sb3 += __shfl_xor(sb3, off);
        }
        if (n < 4) {   // Es|Fs packed bf16: e^ss, e^{0.2 ss}
            const float v = ((n == 0) ? sa0 : (n == 1) ? sa1 : (n == 2) ? sa2 : sa3) * LOG2E;
            const unsigned int pkv = f2bf(EXP2F(v)) |
                ((unsigned int)f2bf(EXP2F(0.2f * v)) << 16);
            sgE[((size_t)inst * 8 + head) * N_ + n0w + q * 4 + n] = pkv;
        } else if (n >= 8 && n < 12) {   // Ed, Fd fp32
            const int r = n - 8;
            const float v = ((r == 0) ? sb0 : (r == 1) ? sb1 : (r == 2) ? sb2 : sb3) * LOG2E;
            float2 ed;
            ed.x = EXP2F(v);
            ed.y = EXP2F(0.2f * v);
            sgD[((size_t)inst * 8 + head) * N_ + n0w + q * 4 + r] = ed;
        }
    }
}

// ---------------------------------------------------------------------------
// Kernel 2: attention via MFMA, split by conv, factorized softmax. 2048
// blocks: tile = bid&31, conv = (bid>>5)&1, bi = bid>>6. 4 waves, wave owns
// 2 heads. LDS 17.25 KB -> 8 blocks/CU. K-loop: w' = max(Es, Fs*rd), masked
// w' = 1/Ed (per-dst scale cancels in Cacc/Cz) — no exp in the loop. Z via
// second MFMA vs all-ones B; v_perm pack truncates w' to bf16 so Z and
// numerator match. unsafeAtomicAdd into zeroed d_out. ONE __syncthreads.
// ---------------------------------------------------------------------------
__global__ __launch_bounds__(256) void attn_kernel(
    const unsigned short* __restrict__ xpt,
    const unsigned int* __restrict__ sgE,
    const float2* __restrict__ sgD,
    const unsigned short* __restrict__ mg,
    const float* __restrict__ bias,
    float* __restrict__ hout)
{
    __shared__ unsigned int es_l[8 * N_];   // 16 KB [h][s] (Es|Fs bf16 pair)
    __shared__ unsigned short mask_l[N_];   // 1 KB

    const int bid = blockIdx.x;
    const int tile = bid & 31;
    const int cj   = (bid >> 5) & 1;
    const int bi   = bid >> 6;
    const int inst = bi * 2 + cj;
    const int ij = (bi & 1) * 2 + cj;
    const int d0 = tile * 16;
    const int t = threadIdx.x;
    const int wave = t >> 6, L = t & 63, n = L & 15, q = L >> 4;
    const int h0 = wave * 2;
    const int n16 = n + 16;

    // stage Es|Fs (4096 u32) + masks (512 u16)
    {
        const uint4* src = (const uint4*)(sgE + (size_t)inst * 8 * N_);
        uint4* dst = (uint4*)es_l;
#pragma unroll
        for (int r = 0; r < 4; ++r) dst[r * 256 + t] = src[r * 256 + t];
    }
    if (t < 64)
        ((uint4*)mask_l)[t] =
            ((const uint4*)(mg + ((size_t)inst * 32 + tile) * N_))[t];

    // per-(hh) dst factors: iEd = 1/Ed, rd = Fd/Ed
    float iEd[2], rd[2];
#pragma unroll
    for (int hh = 0; hh < 2; ++hh) {
        const float2 ed = sgD[((size_t)inst * 8 + h0 + hh) * N_ + d0 + n];
        iEd[hh] = 1.0f / ed.x;
        rd[hh] = ed.y * iEd[hh];
    }

    __syncthreads();   // the ONLY barrier

    const unsigned short* xpi = xpt + (size_t)inst * D_ * N_;

    const uintx4 ou = { 0x3F803F80u, 0x3F803F80u, 0x3F803F80u, 0x3F803F80u };
    const short8 onesB = __builtin_bit_cast(short8, ou);

    floatx4 Cacc[2] = { (floatx4){0.f,0.f,0.f,0.f}, (floatx4){0.f,0.f,0.f,0.f} };
    floatx4 Cz[2]   = { (floatx4){0.f,0.f,0.f,0.f}, (floatx4){0.f,0.f,0.f,0.f} };

    // software-prefetched, barrier-free K loop: 16 chunks of 32 s
    short8 Bf0 = *(const short8*)(xpi + (size_t)(h0 * 16 + n) * N_ + q * 8);
    short8 Bf1 = *(const short8*)(xpi + (size_t)((h0 + 1) * 16 + n) * N_ + q * 8);
    for (int c = 0; c < 16; ++c) {
        const int sq = c * 32 + q * 8;
        short8 nB0, nB1;
        if (c < 15) {
            nB0 = *(const short8*)(xpi + (size_t)(h0 * 16 + n) * N_ + sq + 32);
            nB1 = *(const short8*)(xpi + (size_t)((h0 + 1) * 16 + n) * N_ + sq + 32);
        }
        const uint4 mv = *(const uint4*)&mask_l[sq];   // 8 u16 masks
        const unsigned int mw[4] = { mv.x, mv.y, mv.z, mv.w };
#pragma unroll
        for (int hh = 0; hh < 2; ++hh) {
            const uint4 e0 = *(const uint4*)&es_l[(h0 + hh) * N_ + sq];
            const uint4 e1 = *(const uint4*)&es_l[(h0 + hh) * N_ + sq + 4];
            const unsigned int epk[8] = { e0.x, e0.y, e0.z, e0.w,
                                          e1.x, e1.y, e1.z, e1.w };
            unsigned int wt[8];
#pragma unroll
            for (int idx = 0; idx < 8; ++idx) {
                const float Es = bflo(epk[idx]);
                const float Fs = bfhi(epk[idx]);
                const float wv = fmaxf(Es, Fs * rd[hh]);
                const unsigned int bit =
                    (mw[idx >> 1] >> ((idx & 1) ? n16 : n)) & 1u;
                wt[idx] = __float_as_uint(bit ? wv : iEd[hh]);
            }
            uintx4 au;   // v_perm keeps bytes 3:2 of each src = bf16 trunc
            au.x = __builtin_amdgcn_perm(wt[1], wt[0], 0x07060302);
            au.y = __builtin_amdgcn_perm(wt[3], wt[2], 0x07060302);
            au.z = __builtin_amdgcn_perm(wt[5], wt[4], 0x07060302);
            au.w = __builtin_amdgcn_perm(wt[7], wt[6], 0x07060302);
            const short8 As = __builtin_bit_cast(short8, au);
            Cacc[hh] = __builtin_amdgcn_mfma_f32_16x16x32_bf16(
                As, hh ? Bf1 : Bf0, Cacc[hh], 0, 0, 0);
            Cz[hh] = __builtin_amdgcn_mfma_f32_16x16x32_bf16(
                As, onesB, Cz[hh], 0, 0, 0);
        }
        Bf0 = nB0;
        Bf1 = nB1;
    }

    // epilogue: atomically add this conv's full term (Ed cancels in ratio)
#pragma unroll
    for (int hh = 0; hh < 2; ++hh) {
        const int h = h0 + hh;
        const float bv = bias[ij * D_ + h * 16 + n];
        const uint2 sv = *(const uint2*)(xpi + (size_t)(h * 16 + n) * N_ + d0 + q * 4);
        const float selfv[4] = { bflo(sv.x), bfhi(sv.x), bflo(sv.y), bfhi(sv.y) };
#pragma unroll
        for (int reg = 0; reg < 4; ++reg) {
            const float Zi = 1.0f / Cz[hh][reg];
            const float val = Cacc[hh][reg] * Zi + selfv[reg] + bv;
            unsafeAtomicAdd(
                &hout[((size_t)bi * N_ + d0 + q * 4 + reg) * D_ + h * 16 + n], val);
        }
    }
}

// ---------------------------------------------------------------------------
// Kernel 3: in-place mix on d_out (thread owns both i slices of one b).
// ---------------------------------------------------------------------------
__global__ __launch_bounds__(256) void combine_kernel(float* __restrict__ h)
{
    const int idx = blockIdx.x * 256 + threadIdx.x;
    const int b = idx >> 14;
    const int r = idx & 16383;
    float4* p0 = (float4*)h + (size_t)b * 32768 + r;
    float4* p1 = p0 + 16384;
    const float4 a = *p0;
    const float4 o = *p1;
    float4 r0, r1;
    r0.x = 1.5f * a.x + 0.5f * o.x;  r1.x = 1.5f * o.x + 0.5f * a.x;
    r0.y = 1.5f * a.y + 0.5f * o.y;  r1.y = 1.5f * o.y + 0.5f * a.y;
    r0.z = 1.5f * a.z + 0.5f * o.z;  r1.z = 1.5f * o.z + 0.5f * a.z;
    r0.w = 1.5f * a.w + 0.5f * o.w;  r1.w = 1.5f * o.w + 0.5f * a.w;
    *p0 = r0;
    *p1 = r1;
}

extern "C" void kernel_launch(void* const* d_in, const int* in_sizes, int n_in,
                              void* d_out, int out_size, void* d_ws, size_t ws_size,
                              hipStream_t stream)
{
    const float* x   = (const float*)d_in[0];
    const int*   A   = (const int*)d_in[1];
    const float* W   = (const float*)d_in[2];
    const float* pb  = (const float*)d_in[3];
    const float* as_ = (const float*)d_in[4];
    const float* ad_ = (const float*)d_in[5];
    const float* bs  = (const float*)d_in[6];

    unsigned short* xpt = (unsigned short*)d_ws;                 // 8 MB
    unsigned int* sgE = (unsigned int*)(xpt + (size_t)64 * D_ * N_);      // +1 MB
    float2* sgD = (float2*)(sgE + (size_t)64 * 8 * N_);                   // +2 MB
    unsigned short* mg = (unsigned short*)(sgD + (size_t)64 * 8 * N_);    // +2 MB
    float* h = (float*)d_out;

    hipMemsetAsync(d_out, 0, (size_t)out_size * sizeof(float), stream);
    prep_kernel<<<2048, 256, 0, stream>>>(x, W, pb, as_, ad_, A, xpt, sgE, sgD, mg);
    attn_kernel<<<2048, 256, 0, stream>>>(xpt, sgE, sgD, mg, bs, h);
    combine_kernel<<<1024, 256, 0, stream>>>(h);
}